// Round 1
// baseline (386.668 us; speedup 1.0000x reference)
//
#include <hip/hip_runtime.h>

#define B_ 4
#define S_ 1024
#define DMODEL 1024
#define H_ 16
#define DP_ 64

typedef __attribute__((ext_vector_type(8))) short short8;
typedef __attribute__((ext_vector_type(4))) float floatx4;
typedef __attribute__((ext_vector_type(8))) unsigned short ushort8;
typedef __attribute__((ext_vector_type(4))) unsigned short ushort4v;

__device__ __forceinline__ unsigned short f2bf(float x) {
    union { float f; unsigned int u; } c; c.f = x;
    unsigned int r = c.u + 0x7FFFu + ((c.u >> 16) & 1u);
    return (unsigned short)(r >> 16);
}
__device__ __forceinline__ float bf2f(unsigned short b) {
    union { float f; unsigned int u; } c; c.u = ((unsigned int)b) << 16;
    return c.f;
}

// y = A @ W^T + bias.  A: [4096,1024] fp32, W: [128*gridDim.x,1024] fp32.
// mode 0: out bf16 head-split [B,H,S,DP].  mode 1: out fp32 [M,N].
__global__ __launch_bounds__(256) void gemm128(
    const float* __restrict__ A, const float* __restrict__ W,
    const float* __restrict__ bias, void* __restrict__ Out, const int mode)
{
    __shared__ unsigned short As[128 * 40];
    __shared__ unsigned short Bs[128 * 40];
    const int tid = threadIdx.x;
    const int w = tid >> 6, lane = tid & 63;
    const int wr = w >> 1, wc = w & 1;
    const int l15 = lane & 15, l4 = lane >> 4;
    const int row0 = blockIdx.y * 128, col0 = blockIdx.x * 128;

    floatx4 acc[4][4];
    const floatx4 z4 = {0.f, 0.f, 0.f, 0.f};
    for (int i = 0; i < 4; i++)
        for (int j = 0; j < 4; j++) acc[i][j] = z4;

    const int sr = tid >> 3;          // staging row base (idx = tid + i*256 -> row = sr + i*32)
    const int sc = (tid & 7) * 4;     // staging col (fp32 elements)

    for (int kk = 0; kk < DMODEL; kk += 32) {
        for (int i = 0; i < 4; i++) {
            const int r = sr + i * 32;
            float4 a = *(const float4*)(A + (size_t)(row0 + r) * DMODEL + kk + sc);
            float4 b = *(const float4*)(W + (size_t)(col0 + r) * DMODEL + kk + sc);
            ushort4v ap, bp;
            ap.x = f2bf(a.x); ap.y = f2bf(a.y); ap.z = f2bf(a.z); ap.w = f2bf(a.w);
            bp.x = f2bf(b.x); bp.y = f2bf(b.y); bp.z = f2bf(b.z); bp.w = f2bf(b.w);
            *(ushort4v*)(&As[r * 40 + sc]) = ap;
            *(ushort4v*)(&Bs[r * 40 + sc]) = bp;
        }
        __syncthreads();
        short8 af[4], bfv[4];
        for (int t = 0; t < 4; t++) {
            af[t]  = *(const short8*)(&As[(wr * 64 + t * 16 + l15) * 40 + l4 * 8]);
            bfv[t] = *(const short8*)(&Bs[(wc * 64 + t * 16 + l15) * 40 + l4 * 8]);
        }
        for (int mt = 0; mt < 4; mt++)
            for (int nt = 0; nt < 4; nt++)
                acc[mt][nt] = __builtin_amdgcn_mfma_f32_16x16x32_bf16(
                    af[mt], bfv[nt], acc[mt][nt], 0, 0, 0);
        __syncthreads();
    }

    if (mode == 0) {
        unsigned short* O = (unsigned short*)Out;
        for (int nt = 0; nt < 4; nt++) {
            const int gn = col0 + wc * 64 + nt * 16 + l15;
            const float bv = bias[gn];
            const int h = gn >> 6, d = gn & 63;
            for (int mt = 0; mt < 4; mt++) {
                const int gmb = row0 + wr * 64 + mt * 16 + l4 * 4;
                for (int i = 0; i < 4; i++) {
                    const int gm = gmb + i;
                    const int b = gm >> 10, s = gm & 1023;
                    O[(((size_t)(b * H_ + h)) * S_ + s) * DP_ + d] =
                        f2bf(acc[mt][nt][i] + bv);
                }
            }
        }
    } else {
        float* O = (float*)Out;
        for (int nt = 0; nt < 4; nt++) {
            const int gn = col0 + wc * 64 + nt * 16 + l15;
            const float bv = bias[gn];
            for (int mt = 0; mt < 4; mt++) {
                const int gmb = row0 + wr * 64 + mt * 16 + l4 * 4;
                for (int i = 0; i < 4; i++)
                    O[(size_t)(gmb + i) * DMODEL + gn] = acc[mt][nt][i] + bv;
            }
        }
    }
}

// Vh [B,H,S,DP] bf16 -> Vt [B,H,DP,S] bf16
__global__ __launch_bounds__(256) void transpose64(
    const unsigned short* __restrict__ Vh, unsigned short* __restrict__ Vt)
{
    __shared__ unsigned short T[64 * 72];
    const int st = blockIdx.x;   // s-tile 0..15
    const int bh = blockIdx.y;   // 0..63
    const int tid = threadIdx.x;
    const unsigned short* src = Vh + ((size_t)bh * S_ + st * 64) * DP_;
    for (int i = 0; i < 2; i++) {
        const int idx = tid + i * 256;
        const int r = idx >> 3, seg = idx & 7;
        *(ushort8*)(&T[r * 72 + seg * 8]) =
            *(const ushort8*)(src + (size_t)r * DP_ + seg * 8);
    }
    __syncthreads();
    unsigned short* dst = Vt + ((size_t)bh * DP_) * S_ + st * 64;
    for (int i = 0; i < 2; i++) {
        const int idx = tid + i * 256;
        const int d = idx >> 3, seg = idx & 7;
        ushort8 o;
        for (int j = 0; j < 8; j++) o[j] = T[(seg * 8 + j) * 72 + d];
        *(ushort8*)(dst + (size_t)d * S_ + seg * 8) = o;
    }
}

// Flash attention: grid (S/64, H, B), 256 threads = 4 waves, wave w owns 16 q rows.
__global__ __launch_bounds__(256) void attn_fwd(
    const unsigned short* __restrict__ Qh, const unsigned short* __restrict__ Kh,
    const unsigned short* __restrict__ Vt, const float* __restrict__ mask,
    float* __restrict__ attnO)
{
    __shared__ unsigned short Ks[64 * 72];
    __shared__ unsigned short Vs[64 * 72];
    __shared__ unsigned short Ps[64 * 72];   // also used for Q staging

    const int qt = blockIdx.x, h = blockIdx.y, b = blockIdx.z;
    const int bh = b * H_ + h;
    const int tid = threadIdx.x, w = tid >> 6, lane = tid & 63;
    const int l15 = lane & 15, l4 = lane >> 4;

    // stage Q tile [64 q][64 d] into Ps
    const unsigned short* qsrc = Qh + ((size_t)bh * S_ + qt * 64) * DP_;
    for (int i = 0; i < 2; i++) {
        const int idx = tid + i * 256;
        const int r = idx >> 3, seg = idx & 7;
        *(ushort8*)(&Ps[r * 72 + seg * 8]) =
            *(const ushort8*)(qsrc + (size_t)r * DP_ + seg * 8);
    }
    __syncthreads();
    short8 aq[2];
    for (int kd = 0; kd < 2; kd++)
        aq[kd] = *(const short8*)(&Ps[(w * 16 + l15) * 72 + kd * 32 + l4 * 8]);

    float m_i[4], l_i[4];
    floatx4 o[4];
    const floatx4 z4 = {0.f, 0.f, 0.f, 0.f};
    for (int i = 0; i < 4; i++) { m_i[i] = -1e30f; l_i[i] = 0.f; o[i] = z4; }

    for (int kt = 0; kt < 16; kt++) {
        // stage K tile [64 key][64 d] and V^T tile [64 d][64 key]
        const unsigned short* ksrc = Kh + ((size_t)bh * S_ + kt * 64) * DP_;
        const unsigned short* vsrc = Vt + (size_t)bh * DP_ * S_ + kt * 64;
        for (int i = 0; i < 2; i++) {
            const int idx = tid + i * 256;
            const int r = idx >> 3, seg = idx & 7;
            *(ushort8*)(&Ks[r * 72 + seg * 8]) =
                *(const ushort8*)(ksrc + (size_t)r * DP_ + seg * 8);
            *(ushort8*)(&Vs[r * 72 + seg * 8]) =
                *(const ushort8*)(vsrc + (size_t)r * S_ + seg * 8);
        }
        __syncthreads();

        // S = Q K^T  (16 q x 64 key per wave)
        floatx4 sa[4];
        for (int nt = 0; nt < 4; nt++) sa[nt] = z4;
        for (int nt = 0; nt < 4; nt++)
            for (int kd = 0; kd < 2; kd++) {
                short8 bk = *(const short8*)(&Ks[(nt * 16 + l15) * 72 + kd * 32 + l4 * 8]);
                sa[nt] = __builtin_amdgcn_mfma_f32_16x16x32_bf16(aq[kd], bk, sa[nt], 0, 0, 0);
            }

        // scale + mask; running row-max
        float vmax[4];
        for (int i = 0; i < 4; i++) vmax[i] = -1e30f;
        for (int nt = 0; nt < 4; nt++) {
            const int key = kt * 64 + nt * 16 + l15;
            for (int i = 0; i < 4; i++) {
                const int q = qt * 64 + w * 16 + l4 * 4 + i;
                float sv = sa[nt][i] * 0.125f + mask[(size_t)q * S_ + key] * (-1e9f);
                sa[nt][i] = sv;
                vmax[i] = fmaxf(vmax[i], sv);
            }
        }
        for (int off = 1; off < 16; off <<= 1)
            for (int i = 0; i < 4; i++)
                vmax[i] = fmaxf(vmax[i], __shfl_xor(vmax[i], off, 64));

        float alpha[4], rsum[4];
        for (int i = 0; i < 4; i++) {
            const float mn = fmaxf(m_i[i], vmax[i]);
            alpha[i] = __expf(m_i[i] - mn);
            m_i[i] = mn;
            rsum[i] = 0.f;
        }
        // P = exp(S - m); write bf16 P to LDS; l-sum uses bf16-rounded values
        for (int nt = 0; nt < 4; nt++)
            for (int i = 0; i < 4; i++) {
                const float p = __expf(sa[nt][i] - m_i[i]);
                const unsigned short pb = f2bf(p);
                Ps[(w * 16 + l4 * 4 + i) * 72 + nt * 16 + l15] = pb;
                rsum[i] += bf2f(pb);
            }
        for (int off = 1; off < 16; off <<= 1)
            for (int i = 0; i < 4; i++)
                rsum[i] += __shfl_xor(rsum[i], off, 64);
        for (int i = 0; i < 4; i++) l_i[i] = l_i[i] * alpha[i] + rsum[i];
        for (int nt = 0; nt < 4; nt++) {
            floatx4 t = o[nt];
            for (int i = 0; i < 4; i++) t[i] *= alpha[i];
            o[nt] = t;
        }
        __syncthreads();

        // O += P V
        for (int nt = 0; nt < 4; nt++)
            for (int kk = 0; kk < 2; kk++) {
                short8 ap = *(const short8*)(&Ps[(w * 16 + l15) * 72 + kk * 32 + l4 * 8]);
                short8 bv = *(const short8*)(&Vs[(nt * 16 + l15) * 72 + kk * 32 + l4 * 8]);
                o[nt] = __builtin_amdgcn_mfma_f32_16x16x32_bf16(ap, bv, o[nt], 0, 0, 0);
            }
        __syncthreads();
    }

    // epilogue: normalize and store fp32 [B,S,D] merged-head
    float inv_l[4];
    for (int i = 0; i < 4; i++) inv_l[i] = 1.0f / l_i[i];
    for (int nt = 0; nt < 4; nt++) {
        const int d = nt * 16 + l15;
        for (int i = 0; i < 4; i++) {
            const int s = qt * 64 + w * 16 + l4 * 4 + i;
            attnO[((size_t)(b * S_ + s)) * DMODEL + h * DP_ + d] = o[nt][i] * inv_l[i];
        }
    }
}

extern "C" void kernel_launch(void* const* d_in, const int* in_sizes, int n_in,
                              void* d_out, int out_size, void* d_ws, size_t ws_size,
                              hipStream_t stream)
{
    (void)in_sizes; (void)n_in; (void)out_size; (void)ws_size;
    const float* q    = (const float*)d_in[0];
    const float* k    = (const float*)d_in[1];
    const float* v    = (const float*)d_in[2];
    const float* mask = (const float*)d_in[3];
    const float* wq_w = (const float*)d_in[4];
    const float* wq_b = (const float*)d_in[5];
    const float* wk_w = (const float*)d_in[6];
    const float* wk_b = (const float*)d_in[7];
    const float* wv_w = (const float*)d_in[8];
    const float* wv_b = (const float*)d_in[9];
    const float* pl_w = (const float*)d_in[10];
    const float* pl_b = (const float*)d_in[11];

    const size_t HS = (size_t)B_ * H_ * S_ * DP_;   // 4M elements
    unsigned short* Qh = (unsigned short*)d_ws;
    unsigned short* Kh = Qh + HS;
    unsigned short* Vh = Kh + HS;
    unsigned short* Vt = Vh + HS;
    float* attnB = (float*)(Vt + HS);               // 16 MB fp32

    dim3 gg(8, 32, 1), bb(256, 1, 1);
    gemm128<<<gg, bb, 0, stream>>>(q, wq_w, wq_b, (void*)Qh, 0);
    gemm128<<<gg, bb, 0, stream>>>(k, wk_w, wk_b, (void*)Kh, 0);
    gemm128<<<gg, bb, 0, stream>>>(v, wv_w, wv_b, (void*)Vh, 0);
    transpose64<<<dim3(16, 64, 1), bb, 0, stream>>>(Vh, Vt);
    attn_fwd<<<dim3(16, 16, 4), bb, 0, stream>>>(Qh, Kh, Vt, mask, attnB);
    gemm128<<<gg, bb, 0, stream>>>(attnB, pl_w, pl_b, d_out, 1);
}

// Round 2
// 241.535 us; speedup vs baseline: 1.6009x; 1.6009x over previous
//
#include <hip/hip_runtime.h>
#include <stdint.h>

#define B_ 4
#define S_ 1024
#define DMODEL 1024
#define H_ 16
#define DP_ 64

typedef __attribute__((ext_vector_type(8))) short short8;
typedef __attribute__((ext_vector_type(4))) float floatx4;
typedef __attribute__((ext_vector_type(8))) unsigned short ushort8;
typedef __attribute__((ext_vector_type(4))) unsigned short ushort4v;

__device__ __forceinline__ unsigned short f2bf(float x) {
    union { float f; unsigned int u; } c; c.f = x;
    unsigned int r = c.u + 0x7FFFu + ((c.u >> 16) & 1u);
    return (unsigned short)(r >> 16);
}
__device__ __forceinline__ float bf2f(unsigned short b) {
    union { float f; unsigned int u; } c; c.u = ((unsigned int)b) << 16;
    return c.f;
}

// async global->LDS, 16B per lane; LDS dest = wave-uniform base + lane*16
#define GLDS16(gp, lp) __builtin_amdgcn_global_load_lds( \
    (const __attribute__((address_space(1))) void*)(gp),  \
    (__attribute__((address_space(3))) void*)(lp), 16, 0, 0)

// ---------------- fp32 -> bf16 bulk convert (q,k,v + 4 weights) ----------------
// 2M groups of 8 elements; segment boundaries are multiples of 256 groups so
// each block is segment-uniform.
__global__ __launch_bounds__(256) void convert_all(
    const float* __restrict__ q, const float* __restrict__ k, const float* __restrict__ v,
    const float* __restrict__ wq, const float* __restrict__ wk, const float* __restrict__ wv,
    const float* __restrict__ wp, unsigned short* __restrict__ ws)
{
    const unsigned g = blockIdx.x * 256u + threadIdx.x;
    const float* s; unsigned short* d; unsigned off;
    if (g < 524288u)        { s = q;  d = ws;            off = g; }
    else if (g < 1048576u)  { s = k;  d = ws + 4194304;  off = g - 524288u; }
    else if (g < 1572864u)  { s = v;  d = ws + 8388608;  off = g - 1048576u; }
    else if (g < 1703936u)  { s = wq; d = ws + 12582912; off = g - 1572864u; }
    else if (g < 1835008u)  { s = wk; d = ws + 13631488; off = g - 1703936u; }
    else if (g < 1966080u)  { s = wv; d = ws + 14680064; off = g - 1835008u; }
    else                    { s = wp; d = ws + 15728640; off = g - 1966080u; }
    const floatx4 a = ((const floatx4*)s)[(size_t)off * 2];
    const floatx4 b = ((const floatx4*)s)[(size_t)off * 2 + 1];
    ushort8 r;
    r[0] = f2bf(a[0]); r[1] = f2bf(a[1]); r[2] = f2bf(a[2]); r[3] = f2bf(a[3]);
    r[4] = f2bf(b[0]); r[5] = f2bf(b[1]); r[6] = f2bf(b[2]); r[7] = f2bf(b[3]);
    ((ushort8*)d)[off] = r;
}

// ---------------- bf16 B^T GEMM: C = X @ W^T + bias ----------------
// X [4096,1024], W [1024,1024], tile 128(M) x 64(N), BK=64, global_load_lds
// staging with XOR col-group swizzle (slot g holds global group g^(row&7)).
// MODE 0: swapped mfma (C^T regs) -> bf16 [B,H,S,64], *scale (Q/K proj)
// MODE 2: normal   -> bf16 Vt [B,H,64,S]                (V proj)
// MODE 3: swapped  -> fp32 [M,N]                        (output proj)
template<int MODE>
__global__ __launch_bounds__(256) void gemm_bt(
    const unsigned short* __restrict__ X, const unsigned short* __restrict__ W,
    const float* __restrict__ bias, void* __restrict__ Out, const float scale)
{
    constexpr bool SWAP = (MODE != 2);
    __shared__ unsigned short Xs[128 * 64];
    __shared__ unsigned short Ws[64 * 64];
    auto* XsL = (__attribute__((address_space(3))) unsigned short*)Xs;
    auto* WsL = (__attribute__((address_space(3))) unsigned short*)Ws;

    const int tid = threadIdx.x, w = tid >> 6, lane = tid & 63;
    const int l15 = lane & 15, l4 = lane >> 4;
    const int lr = lane >> 3;                 // row-within-8 for staging
    const int gsw = (lane & 7) ^ (lr & 7);    // swizzled source col-group
    const int row0 = blockIdx.y * 128, col0 = blockIdx.x * 64;

    floatx4 acc[8];
    for (int i = 0; i < 8; i++) acc[i] = (floatx4){0.f, 0.f, 0.f, 0.f};

    for (int kk = 0; kk < DMODEL; kk += 64) {
        __syncthreads();   // prior-iter frag reads done before overwrite
        for (int j = 0; j < 4; j++) {
            const int rb = w * 32 + j * 8;
            GLDS16(X + (size_t)(row0 + rb + lr) * DMODEL + kk + gsw * 8, XsL + rb * 64);
        }
        for (int j = 0; j < 2; j++) {
            const int rb = w * 16 + j * 8;
            GLDS16(W + (size_t)(col0 + rb + lr) * DMODEL + kk + gsw * 8, WsL + rb * 64);
        }
        __syncthreads();   // barrier drains vmcnt -> staging visible

        for (int ks = 0; ks < 2; ks++) {
            const int slot = ((ks * 4 + l4) ^ (l15 & 7)) * 8;
            short8 xf[2], wf[4];
            for (int t = 0; t < 2; t++)
                xf[t] = *(const short8*)(Xs + (w * 32 + t * 16 + l15) * 64 + slot);
            for (int t = 0; t < 4; t++)
                wf[t] = *(const short8*)(Ws + (t * 16 + l15) * 64 + slot);
            if (SWAP) {
                for (int nt = 0; nt < 4; nt++)
                    for (int mt = 0; mt < 2; mt++)
                        acc[nt * 2 + mt] = __builtin_amdgcn_mfma_f32_16x16x32_bf16(
                            wf[nt], xf[mt], acc[nt * 2 + mt], 0, 0, 0);
            } else {
                for (int mt = 0; mt < 2; mt++)
                    for (int nt = 0; nt < 4; nt++)
                        acc[mt * 4 + nt] = __builtin_amdgcn_mfma_f32_16x16x32_bf16(
                            xf[mt], wf[nt], acc[mt * 4 + nt], 0, 0, 0);
            }
        }
    }

    if constexpr (MODE == 0) {
        unsigned short* O = (unsigned short*)Out;
        for (int nt = 0; nt < 4; nt++) {
            const int n0 = col0 + nt * 16 + l4 * 4;
            const floatx4 bv = *(const floatx4*)(bias + n0);
            const int h = n0 >> 6, d0 = n0 & 63;
            for (int mt = 0; mt < 2; mt++) {
                const int m = row0 + w * 32 + mt * 16 + l15;
                const int b = m >> 10, s = m & 1023;
                const floatx4 a = acc[nt * 2 + mt];
                ushort4v pk;
                for (int i = 0; i < 4; i++) pk[i] = f2bf((a[i] + bv[i]) * scale);
                *(ushort4v*)(O + (((size_t)(b * H_ + h) * S_ + s) * DP_ + d0)) = pk;
            }
        }
    } else if constexpr (MODE == 2) {
        unsigned short* O = (unsigned short*)Out;
        for (int mt = 0; mt < 2; mt++) {
            const int m0 = row0 + w * 32 + mt * 16 + l4 * 4;
            const int b = m0 >> 10, s0 = m0 & 1023;
            for (int nt = 0; nt < 4; nt++) {
                const int n = col0 + nt * 16 + l15;
                const int h = n >> 6, d = n & 63;
                const float bv = bias[n];
                const floatx4 a = acc[mt * 4 + nt];
                ushort4v pk;
                for (int i = 0; i < 4; i++) pk[i] = f2bf(a[i] + bv);
                *(ushort4v*)(O + (((size_t)(b * H_ + h) * DP_ + d) * S_ + s0)) = pk;
            }
        }
    } else {
        float* O = (float*)Out;
        for (int nt = 0; nt < 4; nt++) {
            const int n0 = col0 + nt * 16 + l4 * 4;
            const floatx4 bv = *(const floatx4*)(bias + n0);
            for (int mt = 0; mt < 2; mt++) {
                const int m = row0 + w * 32 + mt * 16 + l15;
                floatx4 ov;
                for (int i = 0; i < 4; i++) ov[i] = acc[nt * 2 + mt][i] + bv[i];
                *(floatx4*)(O + (size_t)m * DMODEL + n0) = ov;
            }
        }
    }
}

// ---------------- flash attention, transposed algebra ----------------
// S^T = K·Q^T (rows=key, cols=q), softmax per q = per-lane (q = lane&15),
// O^T = V^T·P^T. grid (S/64, H, B), 4 waves, wave w owns q = qt*64+w*16..+15.
__global__ __launch_bounds__(256) void attn_fwd(
    const unsigned short* __restrict__ Qh, const unsigned short* __restrict__ Kh,
    const unsigned short* __restrict__ Vt, const float* __restrict__ mask,
    unsigned short* __restrict__ attnO)
{
    __shared__ unsigned short Ks[64 * 64];
    __shared__ unsigned short Vs[64 * 64];
    __shared__ unsigned short Ps[4 * 16 * 72];   // per-wave P [16 q][64 key], pad 72
    auto* KsL = (__attribute__((address_space(3))) unsigned short*)Ks;
    auto* VsL = (__attribute__((address_space(3))) unsigned short*)Vs;

    const int qt = blockIdx.x, h = blockIdx.y, b = blockIdx.z;
    const int bh = b * H_ + h;
    const int tid = threadIdx.x, w = tid >> 6, lane = tid & 63;
    const int l15 = lane & 15, l4 = lane >> 4;
    const int lr = lane >> 3, gsw = (lane & 7) ^ (lr & 7);
    unsigned short* PsW = Ps + w * 16 * 72;
    const int qg = qt * 64 + w * 16 + l15;       // this lane's q row

    // Q as B-operand fragment, straight from global (used every tile)
    short8 aq[2];
    for (int kd = 0; kd < 2; kd++)
        aq[kd] = *(const short8*)(Qh + ((size_t)bh * S_ + qg) * DP_ + kd * 32 + l4 * 8);

    float m_i = -1e30f, l_i = 0.f;
    floatx4 o[4];
    for (int i = 0; i < 4; i++) o[i] = (floatx4){0.f, 0.f, 0.f, 0.f};

    for (int kt = 0; kt < 16; kt++) {
        __syncthreads();
        for (int j = 0; j < 2; j++) {
            const int rb = w * 16 + j * 8;
            GLDS16(Kh + ((size_t)bh * S_ + kt * 64 + rb + lr) * DP_ + gsw * 8, KsL + rb * 64);
            GLDS16(Vt + ((size_t)bh * DP_ + rb + lr) * S_ + kt * 64 + gsw * 8, VsL + rb * 64);
        }
        __syncthreads();

        // S^T init with mask*(-1e9) (keys contiguous per q-row -> float4)
        floatx4 sa[4];
        for (int nt = 0; nt < 4; nt++) {
            const floatx4 mk = *(const floatx4*)(mask + (size_t)qg * S_ + kt * 64 + nt * 16 + l4 * 4);
            for (int i = 0; i < 4; i++) sa[nt][i] = mk[i] * (-1e9f);
        }
        for (int nt = 0; nt < 4; nt++)
            for (int kd = 0; kd < 2; kd++) {
                short8 ak = *(const short8*)(Ks + (nt * 16 + l15) * 64 + (((kd * 4 + l4) ^ (l15 & 7)) * 8));
                sa[nt] = __builtin_amdgcn_mfma_f32_16x16x32_bf16(ak, aq[kd], sa[nt], 0, 0, 0);
            }

        // online softmax, per-lane q
        float mx = sa[0][0];
        for (int nt = 0; nt < 4; nt++)
            for (int i = 0; i < 4; i++) mx = fmaxf(mx, sa[nt][i]);
        mx = fmaxf(mx, __shfl_xor(mx, 16, 64));
        mx = fmaxf(mx, __shfl_xor(mx, 32, 64));
        const float mnew = fmaxf(m_i, mx);
        const float alpha = __expf(m_i - mnew);
        m_i = mnew;

        float rs = 0.f;
        for (int nt = 0; nt < 4; nt++) {
            ushort4v pk;
            for (int i = 0; i < 4; i++) {
                const unsigned short pb = f2bf(__expf(sa[nt][i] - mnew));
                pk[i] = pb;
                rs += bf2f(pb);
            }
            *(ushort4v*)(PsW + l15 * 72 + nt * 16 + l4 * 4) = pk;   // P [q][key], packed
        }
        rs += __shfl_xor(rs, 16, 64);
        rs += __shfl_xor(rs, 32, 64);
        l_i = l_i * alpha + rs;
        for (int mt = 0; mt < 4; mt++)
            for (int i = 0; i < 4; i++) o[mt][i] *= alpha;

        // O^T += V^T · P^T  (A = Vs rows d, B = P rows q — both b128)
        short8 bp[2];
        for (int kc = 0; kc < 2; kc++)
            bp[kc] = *(const short8*)(PsW + l15 * 72 + kc * 32 + l4 * 8);
        for (int mt = 0; mt < 4; mt++)
            for (int kc = 0; kc < 2; kc++) {
                short8 av = *(const short8*)(Vs + (mt * 16 + l15) * 64 + (((kc * 4 + l4) ^ (l15 & 7)) * 8));
                o[mt] = __builtin_amdgcn_mfma_f32_16x16x32_bf16(av, bp[kc], o[mt], 0, 0, 0);
            }
    }

    const float inv = 1.0f / l_i;
    for (int mt = 0; mt < 4; mt++) {
        ushort4v pk;
        for (int i = 0; i < 4; i++) pk[i] = f2bf(o[mt][i] * inv);
        *(ushort4v*)(attnO + ((size_t)(b * S_ + qg)) * DMODEL + h * DP_ + mt * 16 + l4 * 4) = pk;
    }
}

extern "C" void kernel_launch(void* const* d_in, const int* in_sizes, int n_in,
                              void* d_out, int out_size, void* d_ws, size_t ws_size,
                              hipStream_t stream)
{
    (void)in_sizes; (void)n_in; (void)out_size; (void)ws_size;
    const float* q    = (const float*)d_in[0];
    const float* k    = (const float*)d_in[1];
    const float* v    = (const float*)d_in[2];
    const float* mask = (const float*)d_in[3];
    const float* wq_w = (const float*)d_in[4];
    const float* wq_b = (const float*)d_in[5];
    const float* wk_w = (const float*)d_in[6];
    const float* wk_b = (const float*)d_in[7];
    const float* wv_w = (const float*)d_in[8];
    const float* wv_b = (const float*)d_in[9];
    const float* pl_w = (const float*)d_in[10];
    const float* pl_b = (const float*)d_in[11];

    unsigned short* ws = (unsigned short*)d_ws;
    unsigned short* Qx = ws;                 // bf16 q [4096,1024]
    unsigned short* Kx = ws + 4194304;       // bf16 k
    unsigned short* Vx = ws + 8388608;       // bf16 v
    unsigned short* Wq = ws + 12582912;      // bf16 weights [1024,1024]
    unsigned short* Wk = ws + 13631488;
    unsigned short* Wv = ws + 14680064;
    unsigned short* Wp = ws + 15728640;
    unsigned short* Qh = ws + 16777216;      // bf16 [B,H,S,64], pre-scaled 1/8
    unsigned short* Kh = ws + 20971520;      // bf16 [B,H,S,64]
    unsigned short* Vt = Kx;                 // bf16 [B,H,64,S] (Kx dead after K-proj)
    unsigned short* attnB = Qx;              // bf16 [B,S,D]    (Qx dead after Q-proj)

    dim3 bb(256, 1, 1), gg(16, 32, 1);
    convert_all<<<dim3(8192, 1, 1), bb, 0, stream>>>(q, k, v, wq_w, wk_w, wv_w, pl_w, ws);
    gemm_bt<0><<<gg, bb, 0, stream>>>(Qx, Wq, wq_b, Qh, 0.125f);
    gemm_bt<0><<<gg, bb, 0, stream>>>(Kx, Wk, wk_b, Kh, 1.0f);
    gemm_bt<2><<<gg, bb, 0, stream>>>(Vx, Wv, wv_b, Vt, 1.0f);
    attn_fwd<<<dim3(16, H_, B_), bb, 0, stream>>>(Qh, Kh, Vt, mask, attnB);
    gemm_bt<3><<<gg, bb, 0, stream>>>(attnB, Wp, pl_b, d_out, 1.0f);
}

// Round 3
// 232.050 us; speedup vs baseline: 1.6663x; 1.0409x over previous
//
#include <hip/hip_runtime.h>
#include <stdint.h>

#define B_ 4
#define S_ 1024
#define DMODEL 1024
#define H_ 16
#define DP_ 64

typedef __attribute__((ext_vector_type(8))) short short8;
typedef __attribute__((ext_vector_type(4))) float floatx4;
typedef __attribute__((ext_vector_type(8))) unsigned short ushort8;
typedef __attribute__((ext_vector_type(4))) unsigned short ushort4v;

#define LOG2E 1.44269504088896f

__device__ __forceinline__ unsigned short f2bf(float x) {     // RNE
    union { float f; unsigned int u; } c; c.f = x;
    unsigned int r = c.u + 0x7FFFu + ((c.u >> 16) & 1u);
    return (unsigned short)(r >> 16);
}
__device__ __forceinline__ unsigned short f2bf_fast(float x) { // half-up (p>=0)
    union { float f; unsigned int u; } c; c.f = x;
    return (unsigned short)((c.u + 0x8000u) >> 16);
}
__device__ __forceinline__ float bf2f(unsigned short b) {
    union { float f; unsigned int u; } c; c.u = ((unsigned int)b) << 16;
    return c.f;
}

#if __has_builtin(__builtin_amdgcn_exp2f)
#define EXP2(x) __builtin_amdgcn_exp2f(x)
#else
#define EXP2(x) exp2f(x)
#endif

#define GLDS16(gp, lp) __builtin_amdgcn_global_load_lds( \
    (const __attribute__((address_space(1))) void*)(gp),  \
    (__attribute__((address_space(3))) void*)(lp), 16, 0, 0)

// ---------------- fp32 -> bf16 bulk convert ----------------
// segments: q,k,v (524288 groups of 8 each), wq,wk,wv,wp (131072 each),
// mask (131072, scaled by -1e9*log2e). All boundaries multiples of 256.
__global__ __launch_bounds__(256) void convert_all(
    const float* __restrict__ q, const float* __restrict__ k, const float* __restrict__ v,
    const float* __restrict__ wq, const float* __restrict__ wk, const float* __restrict__ wv,
    const float* __restrict__ wp, const float* __restrict__ mask,
    unsigned short* __restrict__ ws)
{
    const unsigned g = blockIdx.x * 256u + threadIdx.x;
    const float* s; unsigned short* d; unsigned off; float sc = 1.0f;
    if (g < 524288u)        { s = q;  d = ws;            off = g; }
    else if (g < 1048576u)  { s = k;  d = ws + 4194304;  off = g - 524288u; }
    else if (g < 1572864u)  { s = v;  d = ws + 8388608;  off = g - 1048576u; }
    else if (g < 1703936u)  { s = wq; d = ws + 12582912; off = g - 1572864u; }
    else if (g < 1835008u)  { s = wk; d = ws + 13631488; off = g - 1703936u; }
    else if (g < 1966080u)  { s = wv; d = ws + 14680064; off = g - 1835008u; }
    else if (g < 2097152u)  { s = wp; d = ws + 15728640; off = g - 1966080u; }
    else { s = mask; d = ws + 16777216; off = g - 2097152u; sc = -1e9f * LOG2E; }
    const floatx4 a = ((const floatx4*)s)[(size_t)off * 2];
    const floatx4 b = ((const floatx4*)s)[(size_t)off * 2 + 1];
    ushort8 r;
    r[0] = f2bf(a[0] * sc); r[1] = f2bf(a[1] * sc); r[2] = f2bf(a[2] * sc); r[3] = f2bf(a[3] * sc);
    r[4] = f2bf(b[0] * sc); r[5] = f2bf(b[1] * sc); r[6] = f2bf(b[2] * sc); r[7] = f2bf(b[3] * sc);
    ((ushort8*)d)[off] = r;
}

// ---------------- GEMM core: 128x128 tile, BK=64, dbuf, GLDS, XOR swizzle ----
// acc[a*4+b2]: SWAP ? (a=nt,b2=mt, C^T regs) : (a=mt,b2=nt).
template<bool SWAP>
__device__ __forceinline__ void gemm_body(
    const unsigned short* __restrict__ X, const unsigned short* __restrict__ W,
    const int row0, const int col0,
    unsigned short* XsBase, unsigned short* WsBase, floatx4* acc)
{
    const int tid = threadIdx.x, w = tid >> 6, lane = tid & 63;
    const int l15 = lane & 15, l4 = lane >> 4;
    const int wr = w >> 1, wc = w & 1;
    const int srow = lane >> 3;              // 0..7
    const int sgrp = (lane & 7) ^ srow;      // swizzled source 16B-group
    auto* XsL = (__attribute__((address_space(3))) unsigned short*)XsBase;
    auto* WsL = (__attribute__((address_space(3))) unsigned short*)WsBase;

    // prologue: stage buffer 0, kk=0
    for (int j = 0; j < 4; j++) {
        const int rb = w * 32 + j * 8;
        GLDS16(X + (size_t)(row0 + rb + srow) * DMODEL + sgrp * 8, XsL + rb * 64);
        GLDS16(W + (size_t)(col0 + rb + srow) * DMODEL + sgrp * 8, WsL + rb * 64);
    }
    for (int it = 0; it < 16; it++) {
        const int cur = it & 1, nxt = cur ^ 1;
        __syncthreads();   // drains vmcnt -> buf cur ready; prior reads of nxt done
        if (it < 15) {
            const int kk = (it + 1) * 64;
            for (int j = 0; j < 4; j++) {
                const int rb = w * 32 + j * 8;
                GLDS16(X + (size_t)(row0 + rb + srow) * DMODEL + kk + sgrp * 8,
                       XsL + nxt * 8192 + rb * 64);
                GLDS16(W + (size_t)(col0 + rb + srow) * DMODEL + kk + sgrp * 8,
                       WsL + nxt * 8192 + rb * 64);
            }
        }
        const unsigned short* Xc = XsBase + cur * 8192;
        const unsigned short* Wc = WsBase + cur * 8192;
        for (int ks = 0; ks < 2; ks++) {
            const int slot = ((ks * 4 + l4) ^ (l15 & 7)) * 8;
            short8 xf[4], wf[4];
            for (int t = 0; t < 4; t++) {
                xf[t] = *(const short8*)(Xc + (wr * 64 + t * 16 + l15) * 64 + slot);
                wf[t] = *(const short8*)(Wc + (wc * 64 + t * 16 + l15) * 64 + slot);
            }
            for (int a = 0; a < 4; a++)
                for (int b2 = 0; b2 < 4; b2++)
                    acc[a * 4 + b2] = SWAP
                        ? __builtin_amdgcn_mfma_f32_16x16x32_bf16(wf[a], xf[b2], acc[a * 4 + b2], 0, 0, 0)
                        : __builtin_amdgcn_mfma_f32_16x16x32_bf16(xf[a], wf[b2], acc[a * 4 + b2], 0, 0, 0);
        }
    }
}

// ---------------- fused QKV projection ----------------
// grid (8, 96): sel = by>>5 (0=Q,1=K,2=V). Q/K: swapped -> bf16 [B,H,S,64]
// (Q pre-scaled by 0.125*log2e). V: normal -> bf16 Vt [B,H,64,S].
__global__ __launch_bounds__(256, 2) void qkv_gemm(
    const unsigned short* __restrict__ Xall, const unsigned short* __restrict__ Wall,
    const float* __restrict__ bq, const float* __restrict__ bk, const float* __restrict__ bv,
    unsigned short* __restrict__ Qh, unsigned short* __restrict__ Kh,
    unsigned short* __restrict__ Vt)
{
    __shared__ unsigned short Xs[2 * 8192];
    __shared__ unsigned short Ws[2 * 8192];
    const int sel = blockIdx.y >> 5;
    const int row0 = (blockIdx.y & 31) * 128, col0 = blockIdx.x * 128;
    const unsigned short* X = Xall + (size_t)sel * 4194304;
    const unsigned short* W = Wall + (size_t)sel * 1048576;
    const float* bias = (sel == 0) ? bq : (sel == 1) ? bk : bv;

    const int tid = threadIdx.x, w = tid >> 6, lane = tid & 63;
    const int l15 = lane & 15, l4 = lane >> 4;
    const int wr = w >> 1, wc = w & 1;

    floatx4 acc[16];
    for (int i = 0; i < 16; i++) acc[i] = (floatx4){0.f, 0.f, 0.f, 0.f};

    if (sel < 2) {
        gemm_body<true>(X, W, row0, col0, Xs, Ws, acc);
        unsigned short* Out = sel ? Kh : Qh;
        const float scale = sel ? 1.0f : 0.125f * LOG2E;
        for (int nt = 0; nt < 4; nt++) {
            const int n0 = col0 + wc * 64 + nt * 16 + l4 * 4;
            const floatx4 bv4 = *(const floatx4*)(bias + n0);
            const int h = n0 >> 6, d0 = n0 & 63;
            for (int mt = 0; mt < 4; mt++) {
                const int m = row0 + wr * 64 + mt * 16 + l15;
                const int b = m >> 10, s = m & 1023;
                const floatx4 a = acc[nt * 4 + mt];
                ushort4v pk;
                for (int i = 0; i < 4; i++) pk[i] = f2bf((a[i] + bv4[i]) * scale);
                *(ushort4v*)(Out + (((size_t)(b * H_ + h) * S_ + s) * DP_ + d0)) = pk;
            }
        }
    } else {
        gemm_body<false>(X, W, row0, col0, Xs, Ws, acc);
        for (int mt = 0; mt < 4; mt++) {
            const int m0 = row0 + wr * 64 + mt * 16 + l4 * 4;
            const int b = m0 >> 10, s0 = m0 & 1023;
            for (int nt = 0; nt < 4; nt++) {
                const int n = col0 + wc * 64 + nt * 16 + l15;
                const int h = n >> 6, d = n & 63;
                const float bvv = bias[n];
                const floatx4 a = acc[mt * 4 + nt];
                ushort4v pk;
                for (int i = 0; i < 4; i++) pk[i] = f2bf(a[i] + bvv);
                *(ushort4v*)(Vt + (((size_t)(b * H_ + h) * DP_ + d) * S_ + s0)) = pk;
            }
        }
    }
}

// ---------------- output projection: fp32 out [M,N] ----------------
__global__ __launch_bounds__(256, 2) void out_gemm(
    const unsigned short* __restrict__ X, const unsigned short* __restrict__ W,
    const float* __restrict__ bias, float* __restrict__ Out)
{
    __shared__ unsigned short Xs[2 * 8192];
    __shared__ unsigned short Ws[2 * 8192];
    const int row0 = blockIdx.y * 128, col0 = blockIdx.x * 128;
    const int tid = threadIdx.x, w = tid >> 6, lane = tid & 63;
    const int l15 = lane & 15, l4 = lane >> 4;
    const int wr = w >> 1, wc = w & 1;

    floatx4 acc[16];
    for (int i = 0; i < 16; i++) acc[i] = (floatx4){0.f, 0.f, 0.f, 0.f};
    gemm_body<true>(X, W, row0, col0, Xs, Ws, acc);

    for (int nt = 0; nt < 4; nt++) {
        const int n0 = col0 + wc * 64 + nt * 16 + l4 * 4;
        const floatx4 bv4 = *(const floatx4*)(bias + n0);
        for (int mt = 0; mt < 4; mt++) {
            const int m = row0 + wr * 64 + mt * 16 + l15;
            floatx4 ov;
            for (int i = 0; i < 4; i++) ov[i] = acc[nt * 4 + mt][i] + bv4[i];
            *(floatx4*)(Out + (size_t)m * DMODEL + n0) = ov;
        }
    }
}

// ---------------- flash attention, transposed algebra, exp2 domain ----------
// grid (S/64, H, B). S^T = K·Q^T (Q pre-scaled), softmax per-lane (q=lane&15),
// O^T = V^T·P^T. K/V double-buffered (1 barrier/tile), mask bf16 pre-scaled.
__global__ __launch_bounds__(256, 4) void attn_fwd(
    const unsigned short* __restrict__ Qh, const unsigned short* __restrict__ Kh,
    const unsigned short* __restrict__ Vt, const unsigned short* __restrict__ maskb,
    unsigned short* __restrict__ attnO)
{
    __shared__ unsigned short Ks[2 * 4096];
    __shared__ unsigned short Vs[2 * 4096];
    __shared__ unsigned short Ps[4 * 1024];    // per-wave [16 q][64], XOR-swizzled
    auto* KsL = (__attribute__((address_space(3))) unsigned short*)Ks;
    auto* VsL = (__attribute__((address_space(3))) unsigned short*)Vs;

    const int qt = blockIdx.x, h = blockIdx.y, b = blockIdx.z;
    const int bh = b * H_ + h;
    const int tid = threadIdx.x, w = tid >> 6, lane = tid & 63;
    const int l15 = lane & 15, l4 = lane >> 4;
    const int srow = lane >> 3, sgrp = (lane & 7) ^ srow;
    unsigned short* PsW = Ps + w * 1024;
    const int qg = qt * 64 + w * 16 + l15;

    short8 aq[2];
    for (int kd = 0; kd < 2; kd++)
        aq[kd] = *(const short8*)(Qh + ((size_t)bh * S_ + qg) * DP_ + kd * 32 + l4 * 8);

    // prologue stage kt=0 into buffer 0
    for (int j = 0; j < 2; j++) {
        const int rb = w * 16 + j * 8;
        GLDS16(Kh + ((size_t)bh * S_ + rb + srow) * DP_ + sgrp * 8, KsL + rb * 64);
        GLDS16(Vt + ((size_t)bh * DP_ + rb + srow) * S_ + sgrp * 8, VsL + rb * 64);
    }

    float m_i = -1e30f, l_i = 0.f;
    floatx4 o[4];
    for (int i = 0; i < 4; i++) o[i] = (floatx4){0.f, 0.f, 0.f, 0.f};

    for (int kt = 0; kt < 16; kt++) {
        const int cur = kt & 1, nxt = cur ^ 1;
        __syncthreads();   // buf cur staged; prior reads of nxt complete
        if (kt < 15) {
            for (int j = 0; j < 2; j++) {
                const int rb = w * 16 + j * 8;
                GLDS16(Kh + ((size_t)bh * S_ + (kt + 1) * 64 + rb + srow) * DP_ + sgrp * 8,
                       KsL + nxt * 4096 + rb * 64);
                GLDS16(Vt + ((size_t)bh * DP_ + rb + srow) * S_ + (kt + 1) * 64 + sgrp * 8,
                       VsL + nxt * 4096 + rb * 64);
            }
        }
        // mask prefetch (bf16, pre-scaled by -1e9*log2e)
        ushort4v mk[4];
        for (int nt = 0; nt < 4; nt++)
            mk[nt] = *(const ushort4v*)(maskb + (size_t)qg * S_ + kt * 64 + nt * 16 + l4 * 4);

        // S^T = K·Q^T (log2 domain)
        const unsigned short* Kc = Ks + cur * 4096;
        const unsigned short* Vc = Vs + cur * 4096;
        floatx4 sa[4];
        for (int nt = 0; nt < 4; nt++) sa[nt] = (floatx4){0.f, 0.f, 0.f, 0.f};
        for (int nt = 0; nt < 4; nt++)
            for (int kd = 0; kd < 2; kd++) {
                short8 ak = *(const short8*)(Kc + (nt * 16 + l15) * 64 + ((kd * 4 + l4) ^ (l15 & 7)) * 8);
                sa[nt] = __builtin_amdgcn_mfma_f32_16x16x32_bf16(ak, aq[kd], sa[nt], 0, 0, 0);
            }

        // + mask, row max
        float mx = -1e30f;
        for (int nt = 0; nt < 4; nt++)
            for (int i = 0; i < 4; i++) {
                const float sv = sa[nt][i] + bf2f(mk[nt][i]);
                sa[nt][i] = sv;
                mx = fmaxf(mx, sv);
            }
        mx = fmaxf(mx, __shfl_xor(mx, 16, 64));
        mx = fmaxf(mx, __shfl_xor(mx, 32, 64));
        const float mnew = fmaxf(m_i, mx);
        const float alpha = EXP2(m_i - mnew);
        m_i = mnew;

        // P = exp2(S'-m'), packed bf16 into swizzled per-wave LDS; l from fp32 p
        float rs = 0.f;
        for (int nt = 0; nt < 4; nt++) {
            ushort4v pk;
            for (int i = 0; i < 4; i++) {
                const float p = EXP2(sa[nt][i] - mnew);
                rs += p;
                pk[i] = f2bf_fast(p);
            }
            const int slot = ((nt * 2 + (l4 >> 1)) ^ (l15 & 7)) * 8 + (l4 & 1) * 4;
            *(ushort4v*)(PsW + l15 * 64 + slot) = pk;
        }
        rs += __shfl_xor(rs, 16, 64);
        rs += __shfl_xor(rs, 32, 64);
        l_i = l_i * alpha + rs;
        for (int mt = 0; mt < 4; mt++)
            for (int i = 0; i < 4; i++) o[mt][i] *= alpha;

        // O^T += V^T · P^T
        short8 bp[2];
        for (int kc = 0; kc < 2; kc++)
            bp[kc] = *(const short8*)(PsW + l15 * 64 + (((kc * 4 + l4) ^ (l15 & 7)) * 8));
        for (int mt = 0; mt < 4; mt++)
            for (int kc = 0; kc < 2; kc++) {
                short8 av = *(const short8*)(Vc + (mt * 16 + l15) * 64 + ((kc * 4 + l4) ^ (l15 & 7)) * 8);
                o[mt] = __builtin_amdgcn_mfma_f32_16x16x32_bf16(av, bp[kc], o[mt], 0, 0, 0);
            }
    }

    // epilogue: normalize, transpose through per-wave LDS, coalesced 16B stores
    const float inv = 1.0f / l_i;
    for (int mt = 0; mt < 4; mt++) {
        ushort4v pk;
        for (int i = 0; i < 4; i++) pk[i] = f2bf(o[mt][i] * inv);
        const int slot = ((mt * 2 + (l4 >> 1)) ^ (l15 & 7)) * 8 + (l4 & 1) * 4;
        *(ushort4v*)(PsW + l15 * 64 + slot) = pk;
    }
    const int qr = lane >> 2;                    // 0..15
    for (int t = 0; t < 2; t++) {
        const int gp = (lane & 3) * 2 + t;       // d-group 0..7
        ushort8 ov = *(const ushort8*)(PsW + qr * 64 + ((gp ^ (qr & 7)) * 8));
        *(ushort8*)(attnO + ((size_t)(b * S_ + qt * 64 + w * 16 + qr)) * DMODEL + h * DP_ + gp * 8) = ov;
    }
}

extern "C" void kernel_launch(void* const* d_in, const int* in_sizes, int n_in,
                              void* d_out, int out_size, void* d_ws, size_t ws_size,
                              hipStream_t stream)
{
    (void)in_sizes; (void)n_in; (void)out_size; (void)ws_size;
    const float* q    = (const float*)d_in[0];
    const float* k    = (const float*)d_in[1];
    const float* v    = (const float*)d_in[2];
    const float* mask = (const float*)d_in[3];
    const float* wq_w = (const float*)d_in[4];
    const float* wq_b = (const float*)d_in[5];
    const float* wk_w = (const float*)d_in[6];
    const float* wk_b = (const float*)d_in[7];
    const float* wv_w = (const float*)d_in[8];
    const float* wv_b = (const float*)d_in[9];
    const float* pl_w = (const float*)d_in[10];
    const float* pl_b = (const float*)d_in[11];

    unsigned short* ws = (unsigned short*)d_ws;
    unsigned short* Xall  = ws;                  // q,k,v bf16 [3][4096,1024]
    unsigned short* Wall  = ws + 12582912;       // wq,wk,wv bf16 [3][1024,1024]
    unsigned short* Wp    = ws + 15728640;
    unsigned short* maskb = ws + 16777216;       // bf16, pre-scaled
    unsigned short* Qh    = ws + 17825792;       // [B,H,S,64], *0.125*log2e
    unsigned short* Kh    = ws + 22020096;       // [B,H,S,64]
    unsigned short* Vt    = ws + 4194304;        // [B,H,64,S] (Kx dead after QKV)
    unsigned short* attnB = ws;                  // [B,S,D]    (Qx dead after QKV)

    dim3 bb(256, 1, 1);
    convert_all<<<dim3(8704, 1, 1), bb, 0, stream>>>(q, k, v, wq_w, wk_w, wv_w, pl_w, mask, ws);
    qkv_gemm<<<dim3(8, 96, 1), bb, 0, stream>>>(Xall, Wall, wq_b, wk_b, wv_b, Qh, Kh, Vt);
    attn_fwd<<<dim3(16, H_, B_), bb, 0, stream>>>(Qh, Kh, Vt, maskb, attnB);
    out_gemm<<<dim3(8, 32, 1), bb, 0, stream>>>(attnB, Wp, pl_b, (float*)d_out);
}

// Round 4
// 224.952 us; speedup vs baseline: 1.7189x; 1.0316x over previous
//
#include <hip/hip_runtime.h>
#include <stdint.h>

#define B_ 4
#define S_ 1024
#define DMODEL 1024
#define H_ 16
#define DP_ 64

typedef __attribute__((ext_vector_type(8))) short short8;
typedef __attribute__((ext_vector_type(4))) float floatx4;
typedef __attribute__((ext_vector_type(8))) unsigned short ushort8;
typedef __attribute__((ext_vector_type(4))) unsigned short ushort4v;

#define LOG2E 1.44269504088896f

__device__ __forceinline__ unsigned short f2bf(float x) {     // RNE
    union { float f; unsigned int u; } c; c.f = x;
    unsigned int r = c.u + 0x7FFFu + ((c.u >> 16) & 1u);
    return (unsigned short)(r >> 16);
}
__device__ __forceinline__ unsigned short f2bf_fast(float x) { // half-up (p>=0)
    union { float f; unsigned int u; } c; c.f = x;
    return (unsigned short)((c.u + 0x8000u) >> 16);
}
__device__ __forceinline__ float bf2f(unsigned short b) {
    union { float f; unsigned int u; } c; c.u = ((unsigned int)b) << 16;
    return c.f;
}

#if __has_builtin(__builtin_amdgcn_exp2f)
#define EXP2(x) __builtin_amdgcn_exp2f(x)
#else
#define EXP2(x) exp2f(x)
#endif

#define GLDS16(gp, lp) __builtin_amdgcn_global_load_lds( \
    (const __attribute__((address_space(1))) void*)(gp),  \
    (__attribute__((address_space(3))) void*)(lp), 16, 0, 0)

// ---------------- fp32 -> bf16 bulk convert ----------------
__global__ __launch_bounds__(256) void convert_all(
    const float* __restrict__ q, const float* __restrict__ k, const float* __restrict__ v,
    const float* __restrict__ wq, const float* __restrict__ wk, const float* __restrict__ wv,
    const float* __restrict__ wp, const float* __restrict__ mask,
    unsigned short* __restrict__ ws)
{
    const unsigned g = blockIdx.x * 256u + threadIdx.x;
    const float* s; unsigned short* d; unsigned off; float sc = 1.0f;
    if (g < 524288u)        { s = q;  d = ws;            off = g; }
    else if (g < 1048576u)  { s = k;  d = ws + 4194304;  off = g - 524288u; }
    else if (g < 1572864u)  { s = v;  d = ws + 8388608;  off = g - 1048576u; }
    else if (g < 1703936u)  { s = wq; d = ws + 12582912; off = g - 1572864u; }
    else if (g < 1835008u)  { s = wk; d = ws + 13631488; off = g - 1703936u; }
    else if (g < 1966080u)  { s = wv; d = ws + 14680064; off = g - 1835008u; }
    else if (g < 2097152u)  { s = wp; d = ws + 15728640; off = g - 1966080u; }
    else { s = mask; d = ws + 16777216; off = g - 2097152u; sc = -1e9f * LOG2E; }
    const floatx4 a = ((const floatx4*)s)[(size_t)off * 2];
    const floatx4 b = ((const floatx4*)s)[(size_t)off * 2 + 1];
    ushort8 r;
    r[0] = f2bf(a[0] * sc); r[1] = f2bf(a[1] * sc); r[2] = f2bf(a[2] * sc); r[3] = f2bf(a[3] * sc);
    r[4] = f2bf(b[0] * sc); r[5] = f2bf(b[1] * sc); r[6] = f2bf(b[2] * sc); r[7] = f2bf(b[3] * sc);
    ((ushort8*)d)[off] = r;
}

// ---------------- GEMM core: m97-style single buffer, 128x128, BK=64 --------
// acc[a*4+b2]: SWAP ? (a=nt,b2=mt, C^T regs) : (a=mt,b2=nt).
template<bool SWAP>
__device__ __forceinline__ void gemm_body(
    const unsigned short* __restrict__ X, const unsigned short* __restrict__ W,
    const int row0, const int col0,
    unsigned short* Xs, unsigned short* Ws, floatx4* acc)
{
    const int tid = threadIdx.x, w = tid >> 6, lane = tid & 63;
    const int l15 = lane & 15, l4 = lane >> 4;
    const int wr = w >> 1, wc = w & 1;
    const int srow = lane >> 3;              // 0..7
    const int sgrp = (lane & 7) ^ srow;      // swizzled source 16B-group
    auto* XsL = (__attribute__((address_space(3))) unsigned short*)Xs;
    auto* WsL = (__attribute__((address_space(3))) unsigned short*)Ws;

    for (int it = 0; it < 16; it++) {
        const int kk = it * 64;
        __syncthreads();   // prior iteration's frag reads done
        for (int j = 0; j < 4; j++) {
            const int rb = w * 32 + j * 8;
            GLDS16(X + (size_t)(row0 + rb + srow) * DMODEL + kk + sgrp * 8, XsL + rb * 64);
            GLDS16(W + (size_t)(col0 + rb + srow) * DMODEL + kk + sgrp * 8, WsL + rb * 64);
        }
        __syncthreads();   // vmcnt drained -> staging visible
        for (int ks = 0; ks < 2; ks++) {
            const int slot = ((ks * 4 + l4) ^ (l15 & 7)) * 8;
            short8 xf[4], wf[4];
            for (int t = 0; t < 4; t++) {
                xf[t] = *(const short8*)(Xs + (wr * 64 + t * 16 + l15) * 64 + slot);
                wf[t] = *(const short8*)(Ws + (wc * 64 + t * 16 + l15) * 64 + slot);
            }
            for (int a = 0; a < 4; a++)
                for (int b2 = 0; b2 < 4; b2++)
                    acc[a * 4 + b2] = SWAP
                        ? __builtin_amdgcn_mfma_f32_16x16x32_bf16(wf[a], xf[b2], acc[a * 4 + b2], 0, 0, 0)
                        : __builtin_amdgcn_mfma_f32_16x16x32_bf16(xf[a], wf[b2], acc[a * 4 + b2], 0, 0, 0);
        }
    }
}

// ---------------- fused QKV projection ----------------
__global__ __launch_bounds__(256, 3) void qkv_gemm(
    const unsigned short* __restrict__ Xall, const unsigned short* __restrict__ Wall,
    const float* __restrict__ bq, const float* __restrict__ bk, const float* __restrict__ bv,
    unsigned short* __restrict__ Qh, unsigned short* __restrict__ Kh,
    unsigned short* __restrict__ Vt)
{
    __shared__ unsigned short Xs[8192];
    __shared__ unsigned short Ws[8192];
    const int sel = blockIdx.y >> 5;
    const int row0 = (blockIdx.y & 31) * 128, col0 = blockIdx.x * 128;
    const unsigned short* X = Xall + (size_t)sel * 4194304;
    const unsigned short* W = Wall + (size_t)sel * 1048576;
    const float* bias = (sel == 0) ? bq : (sel == 1) ? bk : bv;

    const int tid = threadIdx.x, w = tid >> 6, lane = tid & 63;
    const int l15 = lane & 15, l4 = lane >> 4;
    const int wr = w >> 1, wc = w & 1;

    floatx4 acc[16];
    for (int i = 0; i < 16; i++) acc[i] = (floatx4){0.f, 0.f, 0.f, 0.f};

    if (sel < 2) {
        gemm_body<true>(X, W, row0, col0, Xs, Ws, acc);
        unsigned short* Out = sel ? Kh : Qh;
        const float scale = sel ? 1.0f : 0.125f * LOG2E;
        for (int nt = 0; nt < 4; nt++) {
            const int n0 = col0 + wc * 64 + nt * 16 + l4 * 4;
            const floatx4 bv4 = *(const floatx4*)(bias + n0);
            const int h = n0 >> 6, d0 = n0 & 63;
            for (int mt = 0; mt < 4; mt++) {
                const int m = row0 + wr * 64 + mt * 16 + l15;
                const int b = m >> 10, s = m & 1023;
                const floatx4 a = acc[nt * 4 + mt];
                ushort4v pk;
                for (int i = 0; i < 4; i++) pk[i] = f2bf((a[i] + bv4[i]) * scale);
                *(ushort4v*)(Out + (((size_t)(b * H_ + h) * S_ + s) * DP_ + d0)) = pk;
            }
        }
    } else {
        gemm_body<false>(X, W, row0, col0, Xs, Ws, acc);
        for (int mt = 0; mt < 4; mt++) {
            const int m0 = row0 + wr * 64 + mt * 16 + l4 * 4;
            const int b = m0 >> 10, s0 = m0 & 1023;
            for (int nt = 0; nt < 4; nt++) {
                const int n = col0 + wc * 64 + nt * 16 + l15;
                const int h = n >> 6, d = n & 63;
                const float bvv = bias[n];
                const floatx4 a = acc[mt * 4 + nt];
                ushort4v pk;
                for (int i = 0; i < 4; i++) pk[i] = f2bf(a[i] + bvv);
                *(ushort4v*)(Vt + (((size_t)(b * H_ + h) * DP_ + d) * S_ + s0)) = pk;
            }
        }
    }
}

// ---------------- output projection: fp32 out [M,N] ----------------
__global__ __launch_bounds__(256, 3) void out_gemm(
    const unsigned short* __restrict__ X, const unsigned short* __restrict__ W,
    const float* __restrict__ bias, float* __restrict__ Out)
{
    __shared__ unsigned short Xs[8192];
    __shared__ unsigned short Ws[8192];
    const int row0 = blockIdx.y * 128, col0 = blockIdx.x * 128;
    const int tid = threadIdx.x, w = tid >> 6, lane = tid & 63;
    const int l15 = lane & 15, l4 = lane >> 4;
    const int wr = w >> 1, wc = w & 1;

    floatx4 acc[16];
    for (int i = 0; i < 16; i++) acc[i] = (floatx4){0.f, 0.f, 0.f, 0.f};
    gemm_body<true>(X, W, row0, col0, Xs, Ws, acc);

    for (int nt = 0; nt < 4; nt++) {
        const int n0 = col0 + wc * 64 + nt * 16 + l4 * 4;
        const floatx4 bv4 = *(const floatx4*)(bias + n0);
        for (int mt = 0; mt < 4; mt++) {
            const int m = row0 + wr * 64 + mt * 16 + l15;
            floatx4 ov;
            for (int i = 0; i < 4; i++) ov[i] = acc[nt * 4 + mt][i] + bv4[i];
            *(floatx4*)(Out + (size_t)m * DMODEL + n0) = ov;
        }
    }
}

// ---------------- flash attention ----------------
// grid (bh=64, qt=16) so linear id % 8 == bh % 8: all qt blocks of one head on
// one XCD (K/V L2 reuse). Mask loads rotated one tile ahead: consumed from
// registers, loaded alongside GLDS prefetch, waited only at the barrier.
__global__ __launch_bounds__(256, 4) void attn_fwd(
    const unsigned short* __restrict__ Qh, const unsigned short* __restrict__ Kh,
    const unsigned short* __restrict__ Vt, const unsigned short* __restrict__ maskb,
    unsigned short* __restrict__ attnO)
{
    __shared__ unsigned short Ks[2 * 4096];
    __shared__ unsigned short Vs[2 * 4096];
    __shared__ unsigned short Ps[4 * 1024];
    auto* KsL = (__attribute__((address_space(3))) unsigned short*)Ks;
    auto* VsL = (__attribute__((address_space(3))) unsigned short*)Vs;

    const int bh = blockIdx.x, qt = blockIdx.y;
    const int b = bh >> 4, h = bh & 15;
    const int tid = threadIdx.x, w = tid >> 6, lane = tid & 63;
    const int l15 = lane & 15, l4 = lane >> 4;
    const int srow = lane >> 3, sgrp = (lane & 7) ^ srow;
    unsigned short* PsW = Ps + w * 1024;
    const int qg = qt * 64 + w * 16 + l15;

    short8 aq[2];
    for (int kd = 0; kd < 2; kd++)
        aq[kd] = *(const short8*)(Qh + ((size_t)bh * S_ + qg) * DP_ + kd * 32 + l4 * 8);

    // prologue: stage K/V tile 0 + mask tile 0
    for (int j = 0; j < 2; j++) {
        const int rb = w * 16 + j * 8;
        GLDS16(Kh + ((size_t)bh * S_ + rb + srow) * DP_ + sgrp * 8, KsL + rb * 64);
        GLDS16(Vt + ((size_t)bh * DP_ + rb + srow) * S_ + sgrp * 8, VsL + rb * 64);
    }
    ushort4v mk[4];
    for (int nt = 0; nt < 4; nt++)
        mk[nt] = *(const ushort4v*)(maskb + (size_t)qg * S_ + nt * 16 + l4 * 4);

    float m_i = -1e30f, l_i = 0.f;
    floatx4 o[4];
    for (int i = 0; i < 4; i++) o[i] = (floatx4){0.f, 0.f, 0.f, 0.f};

    for (int kt = 0; kt < 16; kt++) {
        const int cur = kt & 1, nxt = cur ^ 1;
        __syncthreads();   // buf cur staged + mask kt in regs; reads of nxt done
        ushort4v mkn[4];
        if (kt < 15) {
            for (int j = 0; j < 2; j++) {
                const int rb = w * 16 + j * 8;
                GLDS16(Kh + ((size_t)bh * S_ + (kt + 1) * 64 + rb + srow) * DP_ + sgrp * 8,
                       KsL + nxt * 4096 + rb * 64);
                GLDS16(Vt + ((size_t)bh * DP_ + rb + srow) * S_ + (kt + 1) * 64 + sgrp * 8,
                       VsL + nxt * 4096 + rb * 64);
            }
            for (int nt = 0; nt < 4; nt++)
                mkn[nt] = *(const ushort4v*)(maskb + (size_t)qg * S_ + (kt + 1) * 64 + nt * 16 + l4 * 4);
        }

        // S^T = K·Q^T (log2 domain; Q pre-scaled by 0.125*log2e)
        const unsigned short* Kc = Ks + cur * 4096;
        const unsigned short* Vc = Vs + cur * 4096;
        floatx4 sa[4];
        for (int nt = 0; nt < 4; nt++) sa[nt] = (floatx4){0.f, 0.f, 0.f, 0.f};
        for (int nt = 0; nt < 4; nt++)
            for (int kd = 0; kd < 2; kd++) {
                short8 ak = *(const short8*)(Kc + (nt * 16 + l15) * 64 + ((kd * 4 + l4) ^ (l15 & 7)) * 8);
                sa[nt] = __builtin_amdgcn_mfma_f32_16x16x32_bf16(ak, aq[kd], sa[nt], 0, 0, 0);
            }

        // + mask (regs), row max
        float mx = -1e30f;
        for (int nt = 0; nt < 4; nt++)
            for (int i = 0; i < 4; i++) {
                const float sv = sa[nt][i] + bf2f(mk[nt][i]);
                sa[nt][i] = sv;
                mx = fmaxf(mx, sv);
            }
        mx = fmaxf(mx, __shfl_xor(mx, 16, 64));
        mx = fmaxf(mx, __shfl_xor(mx, 32, 64));
        const float mnew = fmaxf(m_i, mx);
        const float alpha = EXP2(m_i - mnew);
        m_i = mnew;

        float rs = 0.f;
        for (int nt = 0; nt < 4; nt++) {
            ushort4v pk;
            for (int i = 0; i < 4; i++) {
                const float p = EXP2(sa[nt][i] - mnew);
                rs += p;
                pk[i] = f2bf_fast(p);
            }
            const int slot = ((nt * 2 + (l4 >> 1)) ^ (l15 & 7)) * 8 + (l4 & 1) * 4;
            *(ushort4v*)(PsW + l15 * 64 + slot) = pk;
        }
        rs += __shfl_xor(rs, 16, 64);
        rs += __shfl_xor(rs, 32, 64);
        l_i = l_i * alpha + rs;
        for (int mt = 0; mt < 4; mt++)
            for (int i = 0; i < 4; i++) o[mt][i] *= alpha;

        // O^T += V^T · P^T
        short8 bp[2];
        for (int kc = 0; kc < 2; kc++)
            bp[kc] = *(const short8*)(PsW + l15 * 64 + (((kc * 4 + l4) ^ (l15 & 7)) * 8));
        for (int mt = 0; mt < 4; mt++)
            for (int kc = 0; kc < 2; kc++) {
                short8 av = *(const short8*)(Vc + (mt * 16 + l15) * 64 + ((kc * 4 + l4) ^ (l15 & 7)) * 8);
                o[mt] = __builtin_amdgcn_mfma_f32_16x16x32_bf16(av, bp[kc], o[mt], 0, 0, 0);
            }

        for (int nt = 0; nt < 4; nt++) mk[nt] = mkn[nt];
    }

    // epilogue: normalize, transpose through per-wave LDS, 16B coalesced stores
    const float inv = 1.0f / l_i;
    for (int mt = 0; mt < 4; mt++) {
        ushort4v pk;
        for (int i = 0; i < 4; i++) pk[i] = f2bf(o[mt][i] * inv);
        const int slot = ((mt * 2 + (l4 >> 1)) ^ (l15 & 7)) * 8 + (l4 & 1) * 4;
        *(ushort4v*)(PsW + l15 * 64 + slot) = pk;
    }
    const int qr = lane >> 2;
    for (int t = 0; t < 2; t++) {
        const int gp = (lane & 3) * 2 + t;
        ushort8 ov = *(const ushort8*)(PsW + qr * 64 + ((gp ^ (qr & 7)) * 8));
        *(ushort8*)(attnO + ((size_t)(b * S_ + qt * 64 + w * 16 + qr)) * DMODEL + h * DP_ + gp * 8) = ov;
    }
}

extern "C" void kernel_launch(void* const* d_in, const int* in_sizes, int n_in,
                              void* d_out, int out_size, void* d_ws, size_t ws_size,
                              hipStream_t stream)
{
    (void)in_sizes; (void)n_in; (void)out_size; (void)ws_size;
    const float* q    = (const float*)d_in[0];
    const float* k    = (const float*)d_in[1];
    const float* v    = (const float*)d_in[2];
    const float* mask = (const float*)d_in[3];
    const float* wq_w = (const float*)d_in[4];
    const float* wq_b = (const float*)d_in[5];
    const float* wk_w = (const float*)d_in[6];
    const float* wk_b = (const float*)d_in[7];
    const float* wv_w = (const float*)d_in[8];
    const float* wv_b = (const float*)d_in[9];
    const float* pl_w = (const float*)d_in[10];
    const float* pl_b = (const float*)d_in[11];

    unsigned short* ws = (unsigned short*)d_ws;
    unsigned short* Xall  = ws;                  // q,k,v bf16 [3][4096,1024]
    unsigned short* Wall  = ws + 12582912;       // wq,wk,wv bf16
    unsigned short* Wp    = ws + 15728640;
    unsigned short* maskb = ws + 16777216;       // bf16, *(-1e9*log2e)
    unsigned short* Qh    = ws + 17825792;       // [B,H,S,64], *0.125*log2e
    unsigned short* Kh    = ws + 22020096;       // [B,H,S,64]
    unsigned short* Vt    = ws + 4194304;        // [B,H,64,S] (k-input dead)
    unsigned short* attnB = ws;                  // [B,S,D]    (q-input dead)

    dim3 bb(256, 1, 1);
    convert_all<<<dim3(8704, 1, 1), bb, 0, stream>>>(q, k, v, wq_w, wk_w, wv_w, pl_w, mask, ws);
    qkv_gemm<<<dim3(8, 96, 1), bb, 0, stream>>>(Xall, Wall, wq_b, wk_b, wv_b, Qh, Kh, Vt);
    attn_fwd<<<dim3(64, 16, 1), bb, 0, stream>>>(Qh, Kh, Vt, maskb, attnB);
    out_gemm<<<dim3(8, 32, 1), bb, 0, stream>>>(attnB, Wp, pl_b, (float*)d_out);
}